// Round 6
// baseline (394.189 us; speedup 1.0000x reference)
//
#include <hip/hip_runtime.h>
#include <hip/hip_fp16.h>
#include <stdint.h>

constexpr int N_NODES = 50000;
constexpr int N_EDGES = 800000;
constexpr int HD      = 128;
constexpr int NREL    = 8;
constexpr int NBUCK   = N_NODES * NREL;   // 400000 (dst,etype) buckets

typedef unsigned short ushortT;
using bf16x8 = __attribute__((ext_vector_type(8))) short;
using f32x4  = __attribute__((ext_vector_type(4))) float;

__device__ __forceinline__ float b2f(uint32_t lo16){
  uint32_t x = lo16 << 16; float f; __builtin_memcpy(&f,&x,4); return f;
}
__device__ __forceinline__ uint16_t f2b(float f){
  uint32_t x; __builtin_memcpy(&x,&f,4);
  uint32_t r = (x + 0x7FFFu + ((x>>16)&1u)) >> 16;
  return (uint16_t)r;
}

// ---------------- utility ----------------
__global__ void k_zero2(int* __restrict__ a, int* __restrict__ b, int n){
  int i = blockIdx.x*blockDim.x + threadIdx.x;
  if(i<n){ a[i]=0; b[i]=0; }
}

// ---------------- CSR build over (dst*8+etype) buckets ----------------
__global__ void k_hist(const int* __restrict__ dst, const int* __restrict__ et,
                       int* __restrict__ deg){
  int i = blockIdx.x*blockDim.x + threadIdx.x;
  if(i<N_EDGES) atomicAdd(&deg[dst[i]*NREL + et[i]],1);
}

__global__ void k_scan1(const int* __restrict__ in, int* __restrict__ out,
                        int* __restrict__ part, int n){
  __shared__ int sm[256];
  int t = threadIdx.x; int i = blockIdx.x*256+t;
  int v = (i<n)? in[i] : 0;
  sm[t]=v; __syncthreads();
  for(int off=1; off<256; off<<=1){
    int x = (t>=off)? sm[t-off] : 0;
    __syncthreads();
    sm[t]+=x;
    __syncthreads();
  }
  if(i<n) out[i]=sm[t]-v;       // exclusive within block
  if(t==255) part[blockIdx.x]=sm[255];
}

// single-block chunked scan of the partials (replaces 3 launches)
__global__ void k_scanmid(int* __restrict__ part, int n){
  __shared__ int sm[256];
  __shared__ int carry;
  int t=threadIdx.x;
  if(t==0) carry=0;
  __syncthreads();
  for(int base=0; base<n; base+=256){
    int i=base+t;
    int v=(i<n)? part[i] : 0;
    sm[t]=v; __syncthreads();
    for(int off=1; off<256; off<<=1){
      int x=(t>=off)? sm[t-off] : 0;
      __syncthreads();
      sm[t]+=x;
      __syncthreads();
    }
    int tot = sm[255];
    if(i<n) part[i]=sm[t]-v+carry;
    __syncthreads();
    if(t==0) carry += tot;
    __syncthreads();
  }
}

__global__ void k_scan3(int* __restrict__ out, const int* __restrict__ part, int n){
  int i = blockIdx.x*blockDim.x+threadIdx.x;
  if(i<n) out[i]+=part[blockIdx.x];
}

// edge record: src in low 16 bits, fp16 weight in high 16 bits (4B total)
__global__ void k_scatter(const int* __restrict__ src, const int* __restrict__ et,
                          const float* __restrict__ w, const int* __restrict__ dst,
                          const int* __restrict__ offs, int* __restrict__ cur,
                          uint32_t* __restrict__ es){
  int i = blockIdx.x*blockDim.x + threadIdx.x;
  if(i<N_EDGES){
    int b = dst[i]*NREL + et[i];
    int pos = offs[b] + atomicAdd(&cur[b],1);
    __half h = __float2half(w[i]);
    ushortT hb; __builtin_memcpy(&hb,&h,2);
    es[pos] = (uint32_t)(src[i] & 0xFFFF) | ((uint32_t)hb << 16);
  }
}

// ---------------- f32 -> bf16 table convert ----------------
__global__ void k_f2b(const float* __restrict__ in, ushortT* __restrict__ out, int n4){
  int i = blockIdx.x*blockDim.x + threadIdx.x;
  if(i<n4){
    float4 v = ((const float4*)in)[i];
    ushort4 o;
    o.x=f2b(v.x); o.y=f2b(v.y); o.z=f2b(v.z); o.w=f2b(v.w);
    ((ushort4*)out)[i]=o;
  }
}

// ---------------- Wt[o][r*128+k] = sum_b comp[r,b] V[b,k,o] (both layers) ----
__global__ void k_relw(const float* __restrict__ comp1, const float* __restrict__ V1,
                       const float* __restrict__ comp2, const float* __restrict__ V2,
                       ushortT* __restrict__ Wt1, ushortT* __restrict__ Wt2){
  int t = blockIdx.x*blockDim.x + threadIdx.x;
  int layer = t >> 17;             // 0 or 1 (2*131072 threads)
  t &= 131071;
  const float* comp = layer? comp2 : comp1;
  const float* V    = layer? V2    : V1;
  ushortT* Wt       = layer? Wt2   : Wt1;
  int o  = t >> 10;                // 0..127
  int rk = t & 1023;
  int r  = rk >> 7, k = rk & 127;
  float s=0.f;
  #pragma unroll
  for(int b=0;b<NREL;b++) s += comp[r*NREL+b]*V[(b<<14) + k*HD + o];
  Wt[t]=f2b(s);
}

// ---------------- aggregate-first: 4 buckets per WAVE ----------------
// lane = q*16+f : quarter q owns bucket wave*4+q, lane f covers bytes [f*16,f*16+16)
// Acat[b][128] bf16, b = node*8+r  (== A[node][1024] r-major)
__global__ void __launch_bounds__(256)
k_agg(const ushortT* __restrict__ xb,   // [N][128] bf16 gather table
      const int* __restrict__ offs, const int* __restrict__ deg,
      const uint32_t* __restrict__ es,  // packed (src u16, w fp16)
      ushortT* __restrict__ Acat){
  int wave = blockIdx.x*4 + (threadIdx.x>>6);
  int lane = threadIdx.x & 63;
  int q = lane >> 4, f = lane & 15;
  int b = wave*4 + q;                   // grid sized exactly: NBUCK/4 waves
  int beg = offs[b], cnt = deg[b];
  const uint32_t* ep = es + beg;
  float a[8] = {};
  uint32_t e = 0;
  if(cnt > 0) e = ep[0];                // masked prefetch
  for(int j=0;j<cnt;j++){
    uint32_t ce = e;
    if(j+1 < cnt) e = ep[j+1];          // prefetch next edge while gathering
    ushortT hb = (ushortT)(ce >> 16);
    __half h; __builtin_memcpy(&h,&hb,2);
    float w = __half2float(h);
    int s = (int)(ce & 0xFFFFu);
    bf16x8 v = *(const bf16x8*)&xb[(size_t)s*HD + f*8];
    #pragma unroll
    for(int t=0;t<8;t++) a[t] += w * b2f((uint16_t)v[t]);
  }
  uint32_t pk[4];
  #pragma unroll
  for(int i=0;i<4;i++)
    pk[i] = (uint32_t)f2b(a[2*i]) | ((uint32_t)f2b(a[2*i+1])<<16);
  // wave writes 4 adjacent 256B rows -> 1KB contiguous
  *(uint4*)&Acat[(size_t)b*HD + f*8] = *(uint4*)pk;
}

// ---------------- LDS-free MFMA GEMM: out[M][128] = Acat[M][1024] @ Wt^T -------
// A read exactly once (streaming, line-coalesced 16B/lane frags); B L2-hot.
constexpr int BM=64;
__global__ void __launch_bounds__(256)
k_gemm(const ushortT* __restrict__ A,   // [M][1024] bf16
       const ushortT* __restrict__ Wt,  // [128][1024] bf16 (B transposed)
       const float* __restrict__ bias,
       float* __restrict__ outF,        // layer2 output (f32) or null
       ushortT* __restrict__ outB,      // layer1 output (bf16) or null
       int M, int relu){
  int tid = threadIdx.x;
  int wid = tid>>6, lane = tid&63;
  int l15 = lane&15, lhi = lane>>4;
  int row0 = blockIdx.x*BM;
  int wr = (wid>>1)*32, wc = (wid&1)*64;   // wave tile 32x64
  int r0 = row0 + wr + l15, r1 = r0 + 16;
  if(r0 > M-1) r0 = M-1;
  if(r1 > M-1) r1 = M-1;
  const ushortT* Ap0 = A  + (size_t)r0*1024 + lhi*8;
  const ushortT* Ap1 = A  + (size_t)r1*1024 + lhi*8;
  const ushortT* Bp0 = Wt + (size_t)(wc     + l15)*1024 + lhi*8;
  const ushortT* Bp1 = Wt + (size_t)(wc+16  + l15)*1024 + lhi*8;
  const ushortT* Bp2 = Wt + (size_t)(wc+32  + l15)*1024 + lhi*8;
  const ushortT* Bp3 = Wt + (size_t)(wc+48  + l15)*1024 + lhi*8;
  f32x4 acc[2][4] = {};
  #pragma unroll 4
  for(int kb=0; kb<32; kb++){
    bf16x8 a0 = *(const bf16x8*)(Ap0 + kb*32);
    bf16x8 a1 = *(const bf16x8*)(Ap1 + kb*32);
    bf16x8 b0 = *(const bf16x8*)(Bp0 + kb*32);
    bf16x8 b1 = *(const bf16x8*)(Bp1 + kb*32);
    bf16x8 b2 = *(const bf16x8*)(Bp2 + kb*32);
    bf16x8 b3 = *(const bf16x8*)(Bp3 + kb*32);
    acc[0][0] = __builtin_amdgcn_mfma_f32_16x16x32_bf16(a0,b0,acc[0][0],0,0,0);
    acc[0][1] = __builtin_amdgcn_mfma_f32_16x16x32_bf16(a0,b1,acc[0][1],0,0,0);
    acc[0][2] = __builtin_amdgcn_mfma_f32_16x16x32_bf16(a0,b2,acc[0][2],0,0,0);
    acc[0][3] = __builtin_amdgcn_mfma_f32_16x16x32_bf16(a0,b3,acc[0][3],0,0,0);
    acc[1][0] = __builtin_amdgcn_mfma_f32_16x16x32_bf16(a1,b0,acc[1][0],0,0,0);
    acc[1][1] = __builtin_amdgcn_mfma_f32_16x16x32_bf16(a1,b1,acc[1][1],0,0,0);
    acc[1][2] = __builtin_amdgcn_mfma_f32_16x16x32_bf16(a1,b2,acc[1][2],0,0,0);
    acc[1][3] = __builtin_amdgcn_mfma_f32_16x16x32_bf16(a1,b3,acc[1][3],0,0,0);
  }
  // epilogue: D row=lhi*4+j, col=l15 per 16x16 fragment
  #pragma unroll
  for(int m=0;m<2;m++){
    #pragma unroll
    for(int j=0;j<4;j++){
      int grow = row0 + wr + m*16 + lhi*4 + j;
      if(grow < M){
        #pragma unroll
        for(int n=0;n<4;n++){
          int col = wc + n*16 + l15;
          float v = acc[m][n][j] + bias[col];
          if(relu) v = fmaxf(v, 0.f);
          if(outF) outF[(size_t)grow*HD + col] = v;
          else     outB[(size_t)grow*HD + col] = f2b(v);
        }
      }
    }
  }
}

extern "C" void kernel_launch(void* const* d_in, const int* in_sizes, int n_in,
                              void* d_out, int out_size, void* d_ws, size_t ws_size,
                              hipStream_t stream){
  const float* feat  = (const float*)d_in[0];
  const int*   etyp  = (const int*)  d_in[1];
  const float* ew    = (const float*)d_in[2];
  const int*   src   = (const int*)  d_in[3];
  const int*   dst   = (const int*)  d_in[4];
  const float* comp1 = (const float*)d_in[5];
  const float* V1    = (const float*)d_in[6];
  const float* bias1 = (const float*)d_in[7];
  const float* comp2 = (const float*)d_in[8];
  const float* V2    = (const float*)d_in[9];
  const float* bias2 = (const float*)d_in[10];
  float* out = (float*)d_out;

  char* p = (char*)d_ws;
  auto alloc = [&](size_t bytes)->char* {
    char* q = p; p += (bytes + 255) & ~(size_t)255; return q;
  };
  ushortT* Wt1   = (ushortT*)alloc((size_t)HD*NREL*HD*2);        // 256 KB
  ushortT* Wt2   = (ushortT*)alloc((size_t)HD*NREL*HD*2);        // 256 KB
  ushortT* Acat  = (ushortT*)alloc((size_t)N_NODES*NREL*HD*2);   // 102.4 MB
  ushortT* xb    = (ushortT*)alloc((size_t)N_NODES*HD*2);        // 12.8 MB
  ushortT* hmid  = (ushortT*)alloc((size_t)N_NODES*HD*2);        // 12.8 MB
  int*   deg   = (int*)  alloc((size_t)NBUCK*4);
  int*   offs  = (int*)  alloc((size_t)NBUCK*4);
  int*   cur   = (int*)  alloc((size_t)NBUCK*4);
  int*   part1 = (int*)  alloc(2048*4);
  uint32_t* es = (uint32_t*)alloc((size_t)N_EDGES*4);            // 3.2 MB

  // ---- CSR build over 400k (dst,etype) buckets ----
  int zb = (NBUCK+255)/256;           // 1563
  k_zero2<<<zb,256,0,stream>>>(deg,cur,NBUCK);
  k_hist<<<(N_EDGES+255)/256,256,0,stream>>>(dst,etyp,deg);
  int nb1 = (NBUCK+255)/256;          // 1563
  k_scan1<<<nb1,256,0,stream>>>(deg,offs,part1,NBUCK);
  k_scanmid<<<1,256,0,stream>>>(part1,nb1);
  k_scan3<<<nb1,256,0,stream>>>(offs,part1,NBUCK);
  k_scatter<<<(N_EDGES+255)/256,256,0,stream>>>(src,etyp,ew,dst,offs,cur,es);

  // ---- feature table to bf16; relation weights for both layers ----
  int n4 = N_NODES*HD/4;
  k_f2b<<<(n4+255)/256,256,0,stream>>>(feat, xb, n4);
  k_relw<<<(2*HD*NREL*HD+255)/256,256,0,stream>>>(comp1,V1,comp2,V2,Wt1,Wt2);

  int aggGrid  = NBUCK/16;                // 25000 blocks: 4 waves x 4 buckets each
  int gemmGrid = (N_NODES + BM - 1)/BM;   // 782
  // ---- layer 1 ----
  k_agg<<<aggGrid,256,0,stream>>>(xb,   offs, deg, es, Acat);
  k_gemm<<<gemmGrid,256,0,stream>>>(Acat, Wt1, bias1, nullptr, hmid, N_NODES, 1);
  // ---- layer 2 ----
  k_agg<<<aggGrid,256,0,stream>>>(hmid, offs, deg, es, Acat);
  k_gemm<<<gemmGrid,256,0,stream>>>(Acat, Wt2, bias2, out, nullptr, N_NODES, 0);
}

// Round 7
// 363.950 us; speedup vs baseline: 1.0831x; 1.0831x over previous
//
#include <hip/hip_runtime.h>
#include <hip/hip_fp16.h>
#include <stdint.h>

constexpr int N_NODES = 50000;
constexpr int N_EDGES = 800000;
constexpr int HD      = 128;
constexpr int NREL    = 8;
constexpr int NBUCK   = N_NODES * NREL;   // 400000 (dst,etype) buckets

typedef unsigned short ushortT;
using bf16x8 = __attribute__((ext_vector_type(8))) short;
using f32x4  = __attribute__((ext_vector_type(4))) float;

__device__ __forceinline__ float b2f(uint32_t lo16){
  uint32_t x = lo16 << 16; float f; __builtin_memcpy(&f,&x,4); return f;
}
__device__ __forceinline__ uint16_t f2b(float f){
  uint32_t x; __builtin_memcpy(&x,&f,4);
  uint32_t r = (x + 0x7FFFu + ((x>>16)&1u)) >> 16;
  return (uint16_t)r;
}

// ---------------- utility ----------------
__global__ void k_zero2(int* __restrict__ a, int* __restrict__ b, int n){
  int i = blockIdx.x*blockDim.x + threadIdx.x;
  if(i<n){ a[i]=0; b[i]=0; }
}

// ---------------- CSR build over (dst*8+etype) buckets ----------------
__global__ void k_hist(const int* __restrict__ dst, const int* __restrict__ et,
                       int* __restrict__ deg){
  int i = blockIdx.x*blockDim.x + threadIdx.x;
  if(i<N_EDGES) atomicAdd(&deg[dst[i]*NREL + et[i]],1);
}

__global__ void k_scan1(const int* __restrict__ in, int* __restrict__ out,
                        int* __restrict__ part, int n){
  __shared__ int sm[256];
  int t = threadIdx.x; int i = blockIdx.x*256+t;
  int v = (i<n)? in[i] : 0;
  sm[t]=v; __syncthreads();
  for(int off=1; off<256; off<<=1){
    int x = (t>=off)? sm[t-off] : 0;
    __syncthreads();
    sm[t]+=x;
    __syncthreads();
  }
  if(i<n) out[i]=sm[t]-v;       // exclusive within block
  if(t==255) part[blockIdx.x]=sm[255];
}

// single-block chunked scan of the partials
__global__ void k_scanmid(int* __restrict__ part, int n){
  __shared__ int sm[256];
  __shared__ int carry;
  int t=threadIdx.x;
  if(t==0) carry=0;
  __syncthreads();
  for(int base=0; base<n; base+=256){
    int i=base+t;
    int v=(i<n)? part[i] : 0;
    sm[t]=v; __syncthreads();
    for(int off=1; off<256; off<<=1){
      int x=(t>=off)? sm[t-off] : 0;
      __syncthreads();
      sm[t]+=x;
      __syncthreads();
    }
    int tot = sm[255];
    if(i<n) part[i]=sm[t]-v+carry;
    __syncthreads();
    if(t==0) carry += tot;
    __syncthreads();
  }
}

__global__ void k_scan3(int* __restrict__ out, const int* __restrict__ part, int n){
  int i = blockIdx.x*blockDim.x+threadIdx.x;
  if(i<n) out[i]+=part[blockIdx.x];
}

// edge record: src in low 16 bits, fp16 weight in high 16 bits (4B total)
__global__ void k_scatter(const int* __restrict__ src, const int* __restrict__ et,
                          const float* __restrict__ w, const int* __restrict__ dst,
                          const int* __restrict__ offs, int* __restrict__ cur,
                          uint32_t* __restrict__ es){
  int i = blockIdx.x*blockDim.x + threadIdx.x;
  if(i<N_EDGES){
    int b = dst[i]*NREL + et[i];
    int pos = offs[b] + atomicAdd(&cur[b],1);
    __half h = __float2half(w[i]);
    ushortT hb; __builtin_memcpy(&hb,&h,2);
    es[pos] = (uint32_t)(src[i] & 0xFFFF) | ((uint32_t)hb << 16);
  }
}

// ---------------- f32 -> bf16 table convert ----------------
__global__ void k_f2b(const float* __restrict__ in, ushortT* __restrict__ out, int n4){
  int i = blockIdx.x*blockDim.x + threadIdx.x;
  if(i<n4){
    float4 v = ((const float4*)in)[i];
    ushort4 o;
    o.x=f2b(v.x); o.y=f2b(v.y); o.z=f2b(v.z); o.w=f2b(v.w);
    ((ushort4*)out)[i]=o;
  }
}

// ---------------- Wt[o][r*128+k] = sum_b comp[r,b] V[b,k,o] (both layers) ----
__global__ void k_relw(const float* __restrict__ comp1, const float* __restrict__ V1,
                       const float* __restrict__ comp2, const float* __restrict__ V2,
                       ushortT* __restrict__ Wt1, ushortT* __restrict__ Wt2){
  int t = blockIdx.x*blockDim.x + threadIdx.x;
  int layer = t >> 17;             // 0 or 1 (2*131072 threads)
  t &= 131071;
  const float* comp = layer? comp2 : comp1;
  const float* V    = layer? V2    : V1;
  ushortT* Wt       = layer? Wt2   : Wt1;
  int o  = t >> 10;                // 0..127
  int rk = t & 1023;
  int r  = rk >> 7, k = rk & 127;
  float s=0.f;
  #pragma unroll
  for(int b=0;b<NREL;b++) s += comp[r*NREL+b]*V[(b<<14) + k*HD + o];
  Wt[t]=f2b(s);
}

// gather one (node,rel) bucket's weighted feature sum; lane-quarter slice f
__device__ __forceinline__ void gather_bucket(const ushortT* __restrict__ xb,
    const int* __restrict__ offs, const int* __restrict__ deg,
    const uint32_t* __restrict__ es, int b, int f, uint32_t* pk){
  int beg = offs[b], cnt = deg[b];
  float a[8] = {};
  uint32_t e = 0;
  if(cnt > 0) e = es[beg];              // masked prefetch
  for(int j=0;j<cnt;j++){
    uint32_t ce = e;
    if(j+1 < cnt) e = es[beg+j+1];      // prefetch next edge
    ushortT hb = (ushortT)(ce >> 16);
    __half h; __builtin_memcpy(&h,&hb,2);
    float wv = __half2float(h);
    int s = (int)(ce & 0xFFFFu);
    bf16x8 v = *(const bf16x8*)&xb[(size_t)s*HD + f*8];
    #pragma unroll
    for(int t=0;t<8;t++) a[t] += wv * b2f((uint16_t)v[t]);
  }
  #pragma unroll
  for(int i=0;i<4;i++)
    pk[i] = (uint32_t)f2b(a[2*i]) | ((uint32_t)f2b(a[2*i+1])<<16);
}

// ---------------- fused aggregate + per-relation MFMA ----------------
// Block: 16 nodes. Per relation: 16 wave-quarters gather their (node,r)
// bucket into a 16x128 LDS tile (double-buffered), then each wave does
// 8 MFMAs (its 32-col slice) with B straight from L2-hot Wt.
constexpr int BNODE = 16, LDK = 136;   // 272B row: 4-bank/row shift -> 2-way (free)
__global__ void __launch_bounds__(256)
k_fused(const ushortT* __restrict__ xb,   // [N][128] bf16 gather table
        const ushortT* __restrict__ Wt,   // [128][1024] bf16 (B^T, o-major)
        const int* __restrict__ offs, const int* __restrict__ deg,
        const uint32_t* __restrict__ es,  // packed (src u16, w fp16)
        const float* __restrict__ bias,
        float* __restrict__ outF,         // layer2: f32 out (or null)
        ushortT* __restrict__ outB,       // layer1: bf16 out (or null)
        int relu){
  __shared__ ushortT Asm[2][BNODE][LDK];
  int tid = threadIdx.x;
  int w = tid>>6, lane = tid&63;
  int q = lane>>4, f = lane&15;          // quarter, feature-slice
  int l15 = lane&15, lhi = lane>>4;      // MFMA fragment coords
  int n0 = blockIdx.x*BNODE;
  int nodeq = n0 + w*4 + q;              // this quarter's node
  int rloc = w*4 + q;                    // node-local LDS row
  f32x4 acc[2] = {};

  // prologue: gather relation 0, write buf 0
  uint32_t pk[4];
  gather_bucket(xb, offs, deg, es, nodeq*NREL + 0, f, pk);
  *(uint4*)&Asm[0][rloc][f*8] = *(uint4*)pk;

  for(int r=0; r<NREL; r++){
    __syncthreads();                     // buf (r&1) filled; buf (r&1)^1 free
    int cur = r & 1;
    uint32_t pk2[4];
    if(r+1 < NREL)
      gather_bucket(xb, offs, deg, es, nodeq*NREL + (r+1), f, pk2);
    // MFMA: acc += A_r(16x128) @ W_r(128x128), this wave's 32-col slice
    #pragma unroll
    for(int kk=0;kk<4;kk++){
      bf16x8 af = *(const bf16x8*)&Asm[cur][l15][kk*32 + lhi*8];
      #pragma unroll
      for(int n=0;n<2;n++){
        int col = w*32 + n*16 + l15;
        bf16x8 bf = *(const bf16x8*)&Wt[(size_t)col*1024 + r*HD + kk*32 + lhi*8];
        acc[n] = __builtin_amdgcn_mfma_f32_16x16x32_bf16(af, bf, acc[n], 0,0,0);
      }
    }
    if(r+1 < NREL)
      *(uint4*)&Asm[cur^1][rloc][f*8] = *(uint4*)pk2;
  }

  // epilogue: D row=lhi*4+j, col=l15 per 16x16 fragment
  #pragma unroll
  for(int n=0;n<2;n++){
    #pragma unroll
    for(int j=0;j<4;j++){
      int grow = n0 + lhi*4 + j;
      int col  = w*32 + n*16 + l15;
      float v = acc[n][j] + bias[col];
      if(relu) v = fmaxf(v, 0.f);
      if(outF) outF[(size_t)grow*HD + col] = v;
      else     outB[(size_t)grow*HD + col] = f2b(v);
    }
  }
}

extern "C" void kernel_launch(void* const* d_in, const int* in_sizes, int n_in,
                              void* d_out, int out_size, void* d_ws, size_t ws_size,
                              hipStream_t stream){
  const float* feat  = (const float*)d_in[0];
  const int*   etyp  = (const int*)  d_in[1];
  const float* ew    = (const float*)d_in[2];
  const int*   src   = (const int*)  d_in[3];
  const int*   dst   = (const int*)  d_in[4];
  const float* comp1 = (const float*)d_in[5];
  const float* V1    = (const float*)d_in[6];
  const float* bias1 = (const float*)d_in[7];
  const float* comp2 = (const float*)d_in[8];
  const float* V2    = (const float*)d_in[9];
  const float* bias2 = (const float*)d_in[10];
  float* out = (float*)d_out;

  char* p = (char*)d_ws;
  auto alloc = [&](size_t bytes)->char* {
    char* q = p; p += (bytes + 255) & ~(size_t)255; return q;
  };
  ushortT* Wt1   = (ushortT*)alloc((size_t)HD*NREL*HD*2);      // 256 KB
  ushortT* Wt2   = (ushortT*)alloc((size_t)HD*NREL*HD*2);      // 256 KB
  ushortT* xb    = (ushortT*)alloc((size_t)N_NODES*HD*2);      // 12.8 MB
  ushortT* hmid  = (ushortT*)alloc((size_t)N_NODES*HD*2);      // 12.8 MB
  int*   deg   = (int*)  alloc((size_t)NBUCK*4);
  int*   offs  = (int*)  alloc((size_t)NBUCK*4);
  int*   cur   = (int*)  alloc((size_t)NBUCK*4);
  int*   part1 = (int*)  alloc(2048*4);
  uint32_t* es = (uint32_t*)alloc((size_t)N_EDGES*4);          // 3.2 MB

  // ---- CSR build over 400k (dst,etype) buckets ----
  int zb = (NBUCK+255)/256;           // 1563
  k_zero2<<<zb,256,0,stream>>>(deg,cur,NBUCK);
  k_hist<<<(N_EDGES+255)/256,256,0,stream>>>(dst,etyp,deg);
  int nb1 = (NBUCK+255)/256;          // 1563
  k_scan1<<<nb1,256,0,stream>>>(deg,offs,part1,NBUCK);
  k_scanmid<<<1,256,0,stream>>>(part1,nb1);
  k_scan3<<<nb1,256,0,stream>>>(offs,part1,NBUCK);
  k_scatter<<<(N_EDGES+255)/256,256,0,stream>>>(src,etyp,ew,dst,offs,cur,es);

  // ---- feature table to bf16; relation weights for both layers ----
  int n4 = N_NODES*HD/4;
  k_f2b<<<(n4+255)/256,256,0,stream>>>(feat, xb, n4);
  k_relw<<<(2*HD*NREL*HD+255)/256,256,0,stream>>>(comp1,V1,comp2,V2,Wt1,Wt2);

  int grid = N_NODES/BNODE;            // 3125
  // ---- layer 1 (fused, bf16 out + relu) ----
  k_fused<<<grid,256,0,stream>>>(xb,   Wt1, offs, deg, es, bias1, nullptr, hmid, 1);
  // ---- layer 2 (fused, f32 out) ----
  k_fused<<<grid,256,0,stream>>>(hmid, Wt2, offs, deg, es, bias2, out, nullptr, 0);
}

// Round 8
// 290.271 us; speedup vs baseline: 1.3580x; 1.2538x over previous
//
#include <hip/hip_runtime.h>
#include <hip/hip_fp16.h>
#include <stdint.h>

constexpr int N_NODES = 50000;
constexpr int N_EDGES = 800000;
constexpr int HD      = 128;
constexpr int NREL    = 8;
constexpr int NBUCK   = N_NODES * NREL;   // 400000 (dst,etype) buckets

typedef unsigned short ushortT;
using bf16x8 = __attribute__((ext_vector_type(8))) short;
using f32x4  = __attribute__((ext_vector_type(4))) float;

typedef const __attribute__((address_space(1))) void* gptr_t;
typedef __attribute__((address_space(3))) void* lptr_t;

__device__ __forceinline__ float b2f(uint32_t lo16){
  uint32_t x = lo16 << 16; float f; __builtin_memcpy(&f,&x,4); return f;
}
__device__ __forceinline__ uint16_t f2b(float f){
  uint32_t x; __builtin_memcpy(&x,&f,4);
  uint32_t r = (x + 0x7FFFu + ((x>>16)&1u)) >> 16;
  return (uint16_t)r;
}

// ---------------- CSR build over (dst*8+etype) buckets ----------------
__global__ void k_hist(const int* __restrict__ dst, const int* __restrict__ et,
                       int* __restrict__ deg){
  int i = blockIdx.x*blockDim.x + threadIdx.x;
  if(i<N_EDGES) atomicAdd(&deg[dst[i]*NREL + et[i]],1);
}

__global__ void k_scan1(const int* __restrict__ in, int* __restrict__ out,
                        int* __restrict__ part, int n){
  __shared__ int sm[256];
  int t = threadIdx.x; int i = blockIdx.x*256+t;
  int v = (i<n)? in[i] : 0;
  sm[t]=v; __syncthreads();
  for(int off=1; off<256; off<<=1){
    int x = (t>=off)? sm[t-off] : 0;
    __syncthreads();
    sm[t]+=x;
    __syncthreads();
  }
  if(i<n) out[i]=sm[t]-v;       // exclusive within block
  if(t==255) part[blockIdx.x]=sm[255];
}

// single-block chunked scan of the partials
__global__ void k_scanmid(int* __restrict__ part, int n){
  __shared__ int sm[256];
  __shared__ int carry;
  int t=threadIdx.x;
  if(t==0) carry=0;
  __syncthreads();
  for(int base=0; base<n; base+=256){
    int i=base+t;
    int v=(i<n)? part[i] : 0;
    sm[t]=v; __syncthreads();
    for(int off=1; off<256; off<<=1){
      int x=(t>=off)? sm[t-off] : 0;
      __syncthreads();
      sm[t]+=x;
      __syncthreads();
    }
    int tot = sm[255];
    if(i<n) part[i]=sm[t]-v+carry;
    __syncthreads();
    if(t==0) carry += tot;
    __syncthreads();
  }
}

__global__ void k_scan3(int* __restrict__ out, const int* __restrict__ part, int n){
  int i = blockIdx.x*blockDim.x+threadIdx.x;
  if(i<n) out[i]+=part[blockIdx.x];
}

// edge record: src in low 16 bits, fp16 weight in high 16 bits (4B total)
__global__ void k_scatter(const int* __restrict__ src, const int* __restrict__ et,
                          const float* __restrict__ w, const int* __restrict__ dst,
                          const int* __restrict__ offs, int* __restrict__ cur,
                          uint32_t* __restrict__ es){
  int i = blockIdx.x*blockDim.x + threadIdx.x;
  if(i<N_EDGES){
    int b = dst[i]*NREL + et[i];
    int pos = offs[b] + atomicAdd(&cur[b],1);
    __half h = __float2half(w[i]);
    ushortT hb; __builtin_memcpy(&hb,&h,2);
    es[pos] = (uint32_t)(src[i] & 0xFFFF) | ((uint32_t)hb << 16);
  }
}

// ---------------- fused prep: f2b table convert + relation weights --------
constexpr int F2B_BLOCKS = (N_NODES*HD/4 + 255)/256;   // 6250
__global__ void k_prep(const float* __restrict__ feat,
                       const float* __restrict__ comp1, const float* __restrict__ V1,
                       const float* __restrict__ comp2, const float* __restrict__ V2,
                       ushortT* __restrict__ xb,
                       ushortT* __restrict__ Wt1, ushortT* __restrict__ Wt2){
  if(blockIdx.x < F2B_BLOCKS){
    int i = blockIdx.x*256 + threadIdx.x;
    if(i < N_NODES*HD/4){
      float4 v = ((const float4*)feat)[i];
      ushort4 o;
      o.x=f2b(v.x); o.y=f2b(v.y); o.z=f2b(v.z); o.w=f2b(v.w);
      ((ushort4*)xb)[i]=o;
    }
  } else {
    int t = (blockIdx.x - F2B_BLOCKS)*256 + threadIdx.x;   // 0..262143
    int layer = t >> 17;
    t &= 131071;
    const float* comp = layer? comp2 : comp1;
    const float* V    = layer? V2    : V1;
    ushortT* Wt       = layer? Wt2   : Wt1;
    int o  = t >> 10;                // 0..127
    int rk = t & 1023;
    int r  = rk >> 7, k = rk & 127;
    float s=0.f;
    #pragma unroll
    for(int b=0;b<NREL;b++) s += comp[r*NREL+b]*V[(b<<14) + k*HD + o];
    Wt[t]=f2b(s);
  }
}

// ---------------- aggregate-first: 4 buckets per WAVE ----------------
// lane = q*16+f : quarter q owns bucket wave*4+q, lane f covers bytes [f*16,f*16+16)
// Acat[b][128] bf16, b = node*8+r  (== A[node][1024] r-major)
__global__ void __launch_bounds__(256)
k_agg(const ushortT* __restrict__ xb,   // [N][128] bf16 gather table
      const int* __restrict__ offs, const int* __restrict__ deg,
      const uint32_t* __restrict__ es,  // packed (src u16, w fp16)
      ushortT* __restrict__ Acat){
  int wave = blockIdx.x*4 + (threadIdx.x>>6);
  int lane = threadIdx.x & 63;
  int q = lane >> 4, f = lane & 15;
  int b = wave*4 + q;                   // grid sized exactly: NBUCK/4 waves
  int beg = offs[b], cnt = deg[b];
  const uint32_t* ep = es + beg;
  float a[8] = {};
  uint32_t e = 0;
  if(cnt > 0) e = ep[0];                // masked prefetch
  for(int j=0;j<cnt;j++){
    uint32_t ce = e;
    if(j+1 < cnt) e = ep[j+1];          // prefetch next edge while gathering
    ushortT hb = (ushortT)(ce >> 16);
    __half h; __builtin_memcpy(&h,&hb,2);
    float w = __half2float(h);
    int s = (int)(ce & 0xFFFFu);
    bf16x8 v = *(const bf16x8*)&xb[(size_t)s*HD + f*8];
    #pragma unroll
    for(int t=0;t<8;t++) a[t] += w * b2f((uint16_t)v[t]);
  }
  uint32_t pk[4];
  #pragma unroll
  for(int i=0;i<4;i++)
    pk[i] = (uint32_t)f2b(a[2*i]) | ((uint32_t)f2b(a[2*i+1])<<16);
  // wave writes 4 adjacent 256B rows -> 1KB contiguous
  *(uint4*)&Acat[(size_t)b*HD + f*8] = *(uint4*)pk;
}

// ---------------- pipelined MFMA GEMM: out[M][128] = Acat[M][1024] @ Wt^T ------
// global_load_lds(16B) staging, double-buffered LDS, 1-deep prefetch,
// XOR chunk-swizzle (inverse-swizzled SOURCE + swizzled ds_read; dest linear).
constexpr int GBM=64, GBK=64;
__global__ void __launch_bounds__(256)
k_gemm(const ushortT* __restrict__ A,   // [M+pad][1024] bf16 (padded past M)
       const ushortT* __restrict__ Wt,  // [128][1024] bf16 (B^T, o-major)
       const float* __restrict__ bias,
       float* __restrict__ outF,        // layer2 output (f32) or null
       ushortT* __restrict__ outB,      // layer1 output (bf16) or null
       int relu){
  __shared__ ushortT Asm[2][GBM][GBK];   // 16 KB
  __shared__ ushortT Bsm[2][128][GBK];   // 32 KB
  int tid = threadIdx.x;
  int wid = tid>>6, lane = tid&63;
  int l15 = lane&15, lhi = lane>>4;
  int row0 = blockIdx.x*GBM;
  int wr = (wid>>1)*32, wc = (wid&1)*64;   // wave tile 32 rows x 64 cols
  int srow = lane>>3, schunk = lane&7;     // staging: 8 rows x 8 chunks per issue

  auto stage = [&](int buf, int kt){
    // A: wave wid stages rows wid*16 .. wid*16+15 (2 issues x 8 rows)
    #pragma unroll
    for(int i=0;i<2;i++){
      int r = wid*16 + i*8 + srow;
      int gc = schunk ^ (r&7);             // inverse swizzle on SOURCE
      const ushortT* gp = A + (size_t)(row0 + r)*1024 + kt + gc*8;
      __builtin_amdgcn_global_load_lds((gptr_t)gp,
          (lptr_t)&Asm[buf][wid*16 + i*8][0], 16, 0, 0);
    }
    // B: wave wid stages rows wid*32 .. wid*32+31 (4 issues x 8 rows)
    #pragma unroll
    for(int i=0;i<4;i++){
      int r = wid*32 + i*8 + srow;
      int gc = schunk ^ (r&7);
      const ushortT* gp = Wt + (size_t)r*1024 + kt + gc*8;
      __builtin_amdgcn_global_load_lds((gptr_t)gp,
          (lptr_t)&Bsm[buf][wid*32 + i*8][0], 16, 0, 0);
    }
  };

  f32x4 acc[2][4] = {};
  stage(0, 0);
  asm volatile("s_waitcnt vmcnt(0)" ::: "memory");
  __syncthreads();

  for(int t=0;t<16;t++){
    int cur = t & 1;
    if(t+1 < 16) stage(cur^1, (t+1)*GBK);   // prefetch flies under compute
    #pragma unroll
    for(int kk=0;kk<2;kk++){
      bf16x8 af[2], bfr[4];
      #pragma unroll
      for(int m=0;m<2;m++){
        int r = wr + m*16 + l15;
        int c = (kk*4 + lhi) ^ (r&7);       // swizzled read
        af[m] = *(const bf16x8*)&Asm[cur][r][c*8];
      }
      #pragma unroll
      for(int n=0;n<4;n++){
        int r = wc + n*16 + l15;
        int c = (kk*4 + lhi) ^ (r&7);
        bfr[n] = *(const bf16x8*)&Bsm[cur][r][c*8];
      }
      #pragma unroll
      for(int m=0;m<2;m++)
        #pragma unroll
        for(int n=0;n<4;n++)
          acc[m][n] = __builtin_amdgcn_mfma_f32_16x16x32_bf16(af[m], bfr[n], acc[m][n], 0,0,0);
    }
    asm volatile("s_waitcnt vmcnt(0)" ::: "memory");   // next buf landed
    __syncthreads();
  }

  // epilogue: D row=lhi*4+j, col=l15 per 16x16 fragment
  #pragma unroll
  for(int m=0;m<2;m++){
    #pragma unroll
    for(int j=0;j<4;j++){
      int grow = row0 + wr + m*16 + lhi*4 + j;
      if(grow < N_NODES){
        #pragma unroll
        for(int n=0;n<4;n++){
          int col = wc + n*16 + l15;
          float v = acc[m][n][j] + bias[col];
          if(relu) v = fmaxf(v, 0.f);
          if(outF) outF[(size_t)grow*HD + col] = v;
          else     outB[(size_t)grow*HD + col] = f2b(v);
        }
      }
    }
  }
}

extern "C" void kernel_launch(void* const* d_in, const int* in_sizes, int n_in,
                              void* d_out, int out_size, void* d_ws, size_t ws_size,
                              hipStream_t stream){
  const float* feat  = (const float*)d_in[0];
  const int*   etyp  = (const int*)  d_in[1];
  const float* ew    = (const float*)d_in[2];
  const int*   src   = (const int*)  d_in[3];
  const int*   dst   = (const int*)  d_in[4];
  const float* comp1 = (const float*)d_in[5];
  const float* V1    = (const float*)d_in[6];
  const float* bias1 = (const float*)d_in[7];
  const float* comp2 = (const float*)d_in[8];
  const float* V2    = (const float*)d_in[9];
  const float* bias2 = (const float*)d_in[10];
  float* out = (float*)d_out;

  char* p = (char*)d_ws;
  auto alloc = [&](size_t bytes)->char* {
    char* q = p; p += (bytes + 255) & ~(size_t)255; return q;
  };
  ushortT* Wt1   = (ushortT*)alloc((size_t)HD*NREL*HD*2);        // 256 KB
  ushortT* Wt2   = (ushortT*)alloc((size_t)HD*NREL*HD*2);        // 256 KB
  ushortT* Acat  = (ushortT*)alloc(((size_t)NBUCK*HD + 64*1024)*2); // 102.4MB +pad
  ushortT* xb    = (ushortT*)alloc((size_t)N_NODES*HD*2);        // 12.8 MB
  ushortT* hmid  = (ushortT*)alloc((size_t)N_NODES*HD*2);        // 12.8 MB
  int*   deg   = (int*)  alloc((size_t)NBUCK*4);
  int*   cur   = (int*)  alloc((size_t)NBUCK*4);                 // adjacent to deg
  int*   offs  = (int*)  alloc((size_t)NBUCK*4);
  int*   part1 = (int*)  alloc(2048*4);
  uint32_t* es = (uint32_t*)alloc((size_t)N_EDGES*4);            // 3.2 MB

  // ---- CSR build over 400k (dst,etype) buckets ----
  hipMemsetAsync(deg, 0, (size_t)2*NBUCK*4, stream);             // deg + cur
  k_hist<<<(N_EDGES+255)/256,256,0,stream>>>(dst,etyp,deg);
  int nb1 = (NBUCK+255)/256;          // 1563
  k_scan1<<<nb1,256,0,stream>>>(deg,offs,part1,NBUCK);
  k_scanmid<<<1,256,0,stream>>>(part1,nb1);
  k_scan3<<<nb1,256,0,stream>>>(offs,part1,NBUCK);
  k_scatter<<<(N_EDGES+255)/256,256,0,stream>>>(src,etyp,ew,dst,offs,cur,es);

  // ---- fused prep: bf16 table + relation weights (both layers) ----
  k_prep<<<F2B_BLOCKS + 1024, 256, 0, stream>>>(feat,comp1,V1,comp2,V2,xb,Wt1,Wt2);

  int aggGrid  = NBUCK/16;                 // 25000 blocks: 4 waves x 4 buckets
  int gemmGrid = (N_NODES + GBM - 1)/GBM;  // 782
  // ---- layer 1 ----
  k_agg<<<aggGrid,256,0,stream>>>(xb,   offs, deg, es, Acat);
  k_gemm<<<gemmGrid,256,0,stream>>>(Acat, Wt1, bias1, nullptr, hmid, 1);
  // ---- layer 2 ----
  k_agg<<<aggGrid,256,0,stream>>>(hmid, offs, deg, es, Acat);
  k_gemm<<<gemmGrid,256,0,stream>>>(Acat, Wt2, bias2, out, nullptr, 0);
}